// Round 1
// baseline (87.774 us; speedup 1.0000x reference)
//
#include <hip/hip_runtime.h>
#include <math.h>

#define T 2048
#define D 3
#define P 3
#define NK 11              // 2*KMAX+1
#define SUM_K2 110.0f      // 2*(1+4+9+16+25)
#define TWO_PI_F 6.28318530717958647692f
#define INV_TWO_PI_F 0.15915494309189533577f
#define PI_F 3.14159265358979323846f

#define SPLIT 4
#define SEG 511            // Tp / SPLIT, Tp = T-1-P = 2044 = 4*511

// Torus logmap: wrap to [-pi, pi]. Reference is floor-mod -> [-pi, pi);
// difference only at exact +/-pi boundary (measure-zero for random floats).
__device__ __forceinline__ float wrap_pi(float x) {
    float k = rintf(x * INV_TWO_PI_F);     // v_rndne_f32
    return fmaf(-k, TWO_PI_F, x);          // x - 2pi*k
}

// Each block handles ONE segment of SEG=511 output timesteps of one series.
// Grid = n_series * SPLIT = 2048 blocks -> exactly 8 blocks/CU x 4 waves
// = 32 waves/CU (full occupancy; previous version was 512 blocks, 48 KiB LDS,
// <=12 waves/CU and latency-bound).
__global__ __launch_bounds__(256) void arp_kernel(
    const float* __restrict__ g,
    const float* __restrict__ ar_phi,   // (D,P)
    const float* __restrict__ ar_eta,   // (D,)
    const float* __restrict__ ar_c,     // (D,)
    float* __restrict__ out,            // (n_mc,)
    int n_samples)
{
    // g rows needed per segment: [t0, t0 + SEG + 3]  -> SEG+4 = 515 rows
    // = 1545 floats, +3 slack for float4 alignment of the segment start.
    __shared__ float sg[SEG * 3 + 12 + 4];      // 1549 floats ~ 6.2 KiB
    __shared__ float sdx[(SEG + 3) * 3];        // 1542 floats ~ 6.2 KiB
    __shared__ float wave_sums[4];

    const int blk    = blockIdx.x;
    const int series = blk >> 2;               // / SPLIT
    const int seg    = blk & (SPLIT - 1);
    const int tid    = threadIdx.x;

    const int t0      = seg * SEG;             // first output timestep
    const int start_f = t0 * 3;                // first float of row t0
    const int a0      = start_f & ~3;          // float4-aligned down (<=3 extra)
    const int ofs     = start_f - a0;
    const int nfloat  = SEG * 3 + 12 + ofs;    // 1545..1548
    const int nvec    = (nfloat + 3) >> 2;     // <= 387

    // Phase 1: coalesced float4 load of the segment (+4-row halo) into LDS.
    {
        const float4* src = (const float4*)(g + (size_t)series * (T * D) + a0);
        float4* dst = (float4*)sg;
        for (int i = tid; i < nvec; i += 256) dst[i] = src[i];  // 2 iters/thread
    }
    __syncthreads();

    // Phase 2: each wrapped increment computed exactly once.
    // sdx[r*3+d] = wrap(g[t0+r+1,d] - g[t0+r,d]) ; flat f = r*3+d.
    {
        const int n = (SEG + 3) * 3;           // 1542; ~6 iters/thread
        for (int f = tid; f < n; f += 256)
            sdx[f] = wrap_pi(sg[ofs + f + 3] - sg[ofs + f]);
    }
    __syncthreads();

    // Per-dim parameters (tiny, cache-served) + analytic winding constant.
    float ph[D][P], inv_s2[D], cc[D];
    float Cd_sum = 0.0f;
    #pragma unroll
    for (int d = 0; d < D; ++d) {
        float s = fabsf(ar_eta[d]);            // scale = sqrt(eta^2)
        inv_s2[d] = 1.0f / (s * s);
        cc[d] = ar_c[d];
        #pragma unroll
        for (int j = 0; j < P; ++j) ph[d][j] = ar_phi[d * P + j];
        // Sum over 11 windings of the non-quadratic parts:
        //   -0.5/s^2 * 4pi^2 * SUM_K2  - NK*log(s) - (NK/2)*log(2pi)
        Cd_sum += -0.5f * inv_s2[d] * (4.0f * PI_F * PI_F * SUM_K2)
                  - (float)NK * logf(s)
                  - 0.5f * (float)NK * logf(TWO_PI_F);
    }

    // Phase 3: local t in [0, SEG). Lane LDS stride 12 B -> bank stride 3,
    // coprime with 32 banks -> only the free 2-way wave64 aliasing.
    float acc = 0.0f;
    for (int t = tid; t < SEG; t += 256) {     // 2 iters/thread
        float w[12];                           // dx[t..t+3][d=0..2], contiguous
        #pragma unroll
        for (int m = 0; m < 12; ++m) w[m] = sdx[t * 3 + m];
        #pragma unroll
        for (int d = 0; d < D; ++d) {
            float dy = w[9 + d] - (ph[d][0] * w[6 + d]
                                 + ph[d][1] * w[3 + d]
                                 + ph[d][2] * w[d]);
            float z = dy - cc[d];
            acc += -0.5f * (float)NK * z * z * inv_s2[d];   // -5.5 * z^2 / s^2
        }
    }

    // Wave shuffle reduction, then cross-wave via LDS.
    #pragma unroll
    for (int off = 32; off > 0; off >>= 1) acc += __shfl_down(acc, off, 64);
    const int wave = tid >> 6, lane = tid & 63;
    if (lane == 0) wave_sums[wave] = acc;
    __syncthreads();
    if (tid == 0) {
        float block_sum = wave_sums[0] + wave_sums[1] + wave_sums[2] + wave_sums[3];
        block_sum += (float)SEG * Cd_sum;      // analytic constant, per segment
        const int mc = series / n_samples;
        atomicAdd(&out[mc], block_sum);        // 64 adds/mc, spread in time
    }
}

extern "C" void kernel_launch(void* const* d_in, const int* in_sizes, int n_in,
                              void* d_out, int out_size, void* d_ws, size_t ws_size,
                              hipStream_t stream) {
    const float* g      = (const float*)d_in[0];
    const float* ar_phi = (const float*)d_in[1];
    const float* ar_eta = (const float*)d_in[2];
    const float* ar_c   = (const float*)d_in[3];
    float* out = (float*)d_out;

    const int n_series  = in_sizes[0] / (T * D);   // n_mc * n_samples = 512
    const int n_mc      = out_size;                // 32
    const int n_samples = n_series / n_mc;         // 16

    // d_out is poisoned (0xAA) before every timed launch — zero it ourselves.
    hipMemsetAsync(out, 0, (size_t)out_size * sizeof(float), stream);
    arp_kernel<<<n_series * SPLIT, 256, 0, stream>>>(g, ar_phi, ar_eta, ar_c, out, n_samples);
}

// Round 3
// 70.624 us; speedup vs baseline: 1.2428x; 1.2428x over previous
//
#include <hip/hip_runtime.h>
#include <math.h>

#define T 2048
#define D 3
#define P 3
#define NK 11              // 2*KMAX+1
#define SUM_K2 110.0f      // 2*(1+4+9+16+25)
#define TWO_PI_F 6.28318530717958647692f
#define INV_TWO_PI_F 0.15915494309189533577f
#define PI_F 3.14159265358979323846f

#define SPLIT 4
#define SEG 511            // Tp / SPLIT, Tp = T-1-P = 2044 = 4*511

// Torus logmap: wrap to [-pi, pi]. Reference is floor-mod -> [-pi, pi);
// difference only at exact +/-pi boundary (measure-zero for random floats).
__device__ __forceinline__ float wrap_pi(float x) {
    float k = rintf(x * INV_TWO_PI_F);     // v_rndne_f32
    return fmaf(-k, TWO_PI_F, x);          // x - 2pi*k
}

// Each block handles ONE segment of SEG=511 output timesteps of one series.
// Grid = n_series * SPLIT = 2048 blocks -> exactly 8 blocks/CU x 4 waves
// = 32 waves/CU (full occupancy). Partial sums go to workspace with PLAIN
// stores (2048 disjoint floats). use_ws==0 falls back to the round-0 path
// (device atomicAdd into out[mc]) in case the harness workspace is too small
// — an OOB workspace write is the prime suspect for the round-2 container
// failure.
__global__ __launch_bounds__(256) void arp_kernel(
    const float* __restrict__ g,
    const float* __restrict__ ar_phi,   // (D,P)
    const float* __restrict__ ar_eta,   // (D,)
    const float* __restrict__ ar_c,     // (D,)
    float* __restrict__ partial,        // (n_series*SPLIT,) if use_ws
    float* __restrict__ out,            // (n_mc,) if !use_ws
    int n_samples,
    int use_ws)
{
    // g rows needed per segment: [t0, t0 + SEG + 3]  -> SEG+4 = 515 rows
    // = 1545 floats, +3 slack for float4 alignment of the segment start.
    __shared__ float sg[SEG * 3 + 12 + 4];      // 1549 floats ~ 6.2 KiB
    __shared__ float sdx[(SEG + 3) * 3];        // 1542 floats ~ 6.2 KiB
    __shared__ float wave_sums[4];

    const int blk    = blockIdx.x;
    const int series = blk >> 2;               // / SPLIT
    const int seg    = blk & (SPLIT - 1);
    const int tid    = threadIdx.x;

    const int t0      = seg * SEG;             // first output timestep
    const int start_f = t0 * 3;                // first float of row t0
    const int a0      = start_f & ~3;          // float4-aligned down (<=3 extra)
    const int ofs     = start_f - a0;
    const int nfloat  = SEG * 3 + 12 + ofs;    // 1545..1548
    const int nvec    = (nfloat + 3) >> 2;     // <= 387

    // Phase 1: coalesced float4 load of the segment (+4-row halo) into LDS.
    {
        const float4* src = (const float4*)(g + (size_t)series * (T * D) + a0);
        float4* dst = (float4*)sg;
        for (int i = tid; i < nvec; i += 256) dst[i] = src[i];  // 2 iters/thread
    }
    __syncthreads();

    // Phase 2: each wrapped increment computed exactly once.
    // sdx[r*3+d] = wrap(g[t0+r+1,d] - g[t0+r,d]) ; flat f = r*3+d.
    {
        const int n = (SEG + 3) * 3;           // 1542; ~6 iters/thread
        for (int f = tid; f < n; f += 256)
            sdx[f] = wrap_pi(sg[ofs + f + 3] - sg[ofs + f]);
    }
    __syncthreads();

    // Per-dim parameters (tiny, cache-served) + analytic winding constant.
    float ph[D][P], inv_s2[D], cc[D];
    float Cd_sum = 0.0f;
    #pragma unroll
    for (int d = 0; d < D; ++d) {
        float s = fabsf(ar_eta[d]);            // scale = sqrt(eta^2)
        inv_s2[d] = 1.0f / (s * s);
        cc[d] = ar_c[d];
        #pragma unroll
        for (int j = 0; j < P; ++j) ph[d][j] = ar_phi[d * P + j];
        // Sum over 11 windings of the non-quadratic parts:
        //   -0.5/s^2 * 4pi^2 * SUM_K2  - NK*log(s) - (NK/2)*log(2pi)
        Cd_sum += -0.5f * inv_s2[d] * (4.0f * PI_F * PI_F * SUM_K2)
                  - (float)NK * logf(s)
                  - 0.5f * (float)NK * logf(TWO_PI_F);
    }

    // Phase 3: local t in [0, SEG). Lane LDS stride 12 B -> bank stride 3,
    // coprime with 32 banks -> only the free 2-way wave64 aliasing.
    float acc = 0.0f;
    for (int t = tid; t < SEG; t += 256) {     // 2 iters/thread
        float w[12];                           // dx[t..t+3][d=0..2], contiguous
        #pragma unroll
        for (int m = 0; m < 12; ++m) w[m] = sdx[t * 3 + m];
        #pragma unroll
        for (int d = 0; d < D; ++d) {
            float dy = w[9 + d] - (ph[d][0] * w[6 + d]
                                 + ph[d][1] * w[3 + d]
                                 + ph[d][2] * w[d]);
            float z = dy - cc[d];
            acc += -0.5f * (float)NK * z * z * inv_s2[d];   // -5.5 * z^2 / s^2
        }
    }

    // Wave shuffle reduction, then cross-wave via LDS; one store/block.
    #pragma unroll
    for (int off = 32; off > 0; off >>= 1) acc += __shfl_down(acc, off, 64);
    const int wave = tid >> 6, lane = tid & 63;
    if (lane == 0) wave_sums[wave] = acc;
    __syncthreads();
    if (tid == 0) {
        float block_sum = wave_sums[0] + wave_sums[1] + wave_sums[2] + wave_sums[3];
        block_sum += (float)SEG * Cd_sum;      // analytic constant, per segment
        if (use_ws) {
            partial[blk] = block_sum;          // disjoint store, no contention
        } else {
            const int mc = series / n_samples;
            atomicAdd(&out[mc], block_sum);    // fallback (round-0 semantics)
        }
    }
}

// Block mc sums its per_mc contiguous partials and writes out[mc] directly.
__global__ __launch_bounds__(64) void reduce_kernel(
    const float* __restrict__ partial,
    float* __restrict__ out,
    int per_mc)
{
    const int mc = blockIdx.x;
    float v = 0.0f;
    for (int i = threadIdx.x; i < per_mc; i += 64)
        v += partial[(size_t)mc * per_mc + i];
    #pragma unroll
    for (int off = 32; off > 0; off >>= 1) v += __shfl_down(v, off, 64);
    if (threadIdx.x == 0) out[mc] = v;
}

extern "C" void kernel_launch(void* const* d_in, const int* in_sizes, int n_in,
                              void* d_out, int out_size, void* d_ws, size_t ws_size,
                              hipStream_t stream) {
    const float* g      = (const float*)d_in[0];
    const float* ar_phi = (const float*)d_in[1];
    const float* ar_eta = (const float*)d_in[2];
    const float* ar_c   = (const float*)d_in[3];
    float* out = (float*)d_out;

    const int n_series  = in_sizes[0] / (T * D);   // n_mc * n_samples = 512
    const int n_mc      = out_size;                // 32
    const int n_samples = n_series / n_mc;         // 16
    const int n_blocks  = n_series * SPLIT;        // 2048
    const int per_mc    = n_samples * SPLIT;       // 64 partials per mc

    const int use_ws = (d_ws != nullptr &&
                        ws_size >= (size_t)n_blocks * sizeof(float)) ? 1 : 0;
    float* partial = (float*)d_ws;

    if (!use_ws) {
        // d_out is poisoned (0xAA) before every timed launch — zero it.
        hipMemsetAsync(out, 0, (size_t)out_size * sizeof(float), stream);
    }
    arp_kernel<<<n_blocks, 256, 0, stream>>>(g, ar_phi, ar_eta, ar_c,
                                             partial, out, n_samples, use_ws);
    if (use_ws)
        reduce_kernel<<<n_mc, 64, 0, stream>>>(partial, out, per_mc);
}